// Round 5
// baseline (110.386 us; speedup 1.0000x reference)
//
#include <hip/hip_runtime.h>
#include <hip/hip_bf16.h>

#define N 4096
#define D 128
#define TILE 128
#define LDP 72   // fallback kernel only

typedef __attribute__((ext_vector_type(8))) short short8;
typedef __attribute__((ext_vector_type(4))) float f32x4;
typedef __attribute__((ext_vector_type(4))) _Float16 h16x4;
typedef __attribute__((ext_vector_type(8))) _Float16 h16x8;

#define LOG2E 1.44269504088896340736f
#define LN2   0.69314718055994530942f

#if __has_builtin(__builtin_amdgcn_rcpf)
__device__ __forceinline__ float fast_rcp(float x) { return __builtin_amdgcn_rcpf(x); }
#else
__device__ __forceinline__ float fast_rcp(float x) { return 1.f / x; }
#endif
#if __has_builtin(__builtin_amdgcn_logf)
__device__ __forceinline__ float fast_log2(float x) { return __builtin_amdgcn_logf(x); }
#else
__device__ __forceinline__ float fast_log2(float x) { return __log2f(x); }
#endif
#if __has_builtin(__builtin_amdgcn_exp2f)
__device__ __forceinline__ float fast_exp2(float x) { return __builtin_amdgcn_exp2f(x); }
#else
__device__ __forceinline__ float fast_exp2(float x) { return exp2f(x); }
#endif

__device__ __forceinline__ float sig_nl2(float nl2) {  // sigmoid(x), nl2 = -x*log2e
    return fast_rcp(1.f + fast_exp2(nl2));
}

// ---------------- kernel 0: cast to bf16, exact fp32 row norms, zero accumulators ----------------
__global__ __launch_bounds__(128) void k_prep(
    const float* __restrict__ X, const float* __restrict__ Y,
    __hip_bfloat16* __restrict__ Xb, __hip_bfloat16* __restrict__ Yb,
    float* __restrict__ xn, float* __restrict__ yn,
    float* __restrict__ R, float* __restrict__ TLr, float* __restrict__ sc)
{
    const int row = blockIdx.x, t = threadIdx.x;
    const float vx = X[row * D + t], vy = Y[row * D + t];
    Xb[row * D + t] = __float2bfloat16(vx);
    Yb[row * D + t] = __float2bfloat16(vy);
    float px = vx * vx, py = vy * vy;
#pragma unroll
    for (int m = 1; m < 64; m <<= 1) { px += __shfl_xor(px, m); py += __shfl_xor(py, m); }
    __shared__ float s[2][2];
    if ((t & 63) == 0) { s[t >> 6][0] = px; s[t >> 6][1] = py; }
    __syncthreads();
    if (t == 0) { xn[row] = s[0][0] + s[1][0]; yn[row] = s[0][1] + s[1][1]; }
    const int g = row * D + t;
    if (g < N) { R[g] = 0.f; TLr[g] = 0.f; }
    if (g < 16) sc[g] = 0.f;
}

// ---------------- main pass: barrier-free, LDS-free MFMA + fused epilogue ----------------
// Fragments loaded directly from global (inputs are L2-resident).
// acc[a][b][r]: j = col0 + wj + a*16 + quad*4 + r,  i = row0 + wi + b*16 + l16
// E-file unit U = ((bn*32+bm)*4 + wave)*8 + a*2 + b2; 16B/lane: [b=2*b2: r0..3 | b=2*b2+1: r0..3]
__global__ __launch_bounds__(256) void k_main(
    const __hip_bfloat16* __restrict__ Yb, const __hip_bfloat16* __restrict__ Xb,
    const float* __restrict__ yn, const float* __restrict__ xn,
    float* __restrict__ pos, float* __restrict__ R, float* __restrict__ TLr,
    h16x8* __restrict__ Eg)
{
    const int tid = threadIdx.x;
    const int bm = blockIdx.y, bn = blockIdx.x;
    const int row0 = bm * TILE, col0 = bn * TILE;   // row0 -> i (Y), col0 -> j (X)
    const int lane = tid & 63, wave = tid >> 6;
    const int wj = (wave >> 1) * 64, wi = (wave & 1) * 64;
    const int l16 = lane & 15, quad = lane >> 4;

    f32x4 acc[4][4];
#pragma unroll
    for (int a = 0; a < 4; a++)
#pragma unroll
        for (int b = 0; b < 4; b++) acc[a][b] = f32x4{0.f, 0.f, 0.f, 0.f};

    const short8* Xg = (const short8*)(Xb + (size_t)col0 * D);   // j side (A)
    const short8* Yg = (const short8*)(Yb + (size_t)row0 * D);   // i side (B)

#pragma unroll
    for (int kk = 0; kk < 4; ++kk) {
        short8 af[4], bf[4];
#pragma unroll
        for (int t = 0; t < 4; t++) {
            af[t] = Xg[(wj + t * 16 + l16) * (D / 8) + kk * 4 + quad];
            bf[t] = Yg[(wi + t * 16 + l16) * (D / 8) + kk * 4 + quad];
        }
#pragma unroll
        for (int a = 0; a < 4; a++)
#pragma unroll
            for (int b = 0; b < 4; b++)
                acc[a][b] = __builtin_amdgcn_mfma_f32_16x16x32_bf16(af[a], bf[b], acc[a][b], 0, 0, 0);
    }

    float ynv[4];
#pragma unroll
    for (int b = 0; b < 4; b++) ynv[b] = yn[row0 + wi + b * 16 + l16];

    float sE[4] = {0.f, 0.f, 0.f, 0.f}, sL2[4] = {0.f, 0.f, 0.f, 0.f};
    const bool diagw = (bm == bn) && (wi == wj);
    const unsigned base8 = (((unsigned)bn * 32u + (unsigned)bm) * 4u + (unsigned)wave) * 8u;

#pragma unroll
    for (int a = 0; a < 4; a++) {
        const f32x4 xq = *(const f32x4*)&xn[col0 + wj + a * 16 + quad * 4];
        f32x4 x1;
#pragma unroll
        for (int r = 0; r < 4; r++) x1[r] = xq[r] + 1.f;
#pragma unroll
        for (int b2 = 0; b2 < 2; b2++) {
            h16x8 hv;
#pragma unroll
            for (int bh = 0; bh < 2; bh++) {
                const int b = b2 * 2 + bh;
                float prod = 1.f;
#pragma unroll
                for (int r = 0; r < 4; r++) {
                    float t = fmaxf(fmaf(-2.f, acc[a][b][r], ynv[b] + x1[r]), 1.f);
                    float e = fast_rcp(t);               // exp(L), exact
                    sE[b] += e;
                    prod *= t;                           // t in [1, ~450]; prod^4 <= 4e10
                    hv[bh * 4 + r] = (_Float16)e;
                    if (diagw && (a * 16 + quad * 4 + r) == (b * 16 + l16))
                        pos[row0 + wi + b * 16 + l16] = -LN2 * fast_log2(t);
                }
                sL2[b] += fast_log2(prod);               // 1 log per 4 elements
            }
            Eg[(size_t)(base8 + (unsigned)(a * 2 + b2)) * 64u + (unsigned)lane] = hv;
        }
    }

#pragma unroll
    for (int b = 0; b < 4; b++) {
        float e = sE[b], l = sL2[b];
        e += __shfl_xor(e, 16); e += __shfl_xor(e, 32);
        l += __shfl_xor(l, 16); l += __shfl_xor(l, 32);
        if (lane < 16) {
            atomicAdd(&R[row0 + wi + b * 16 + l16], e);
            atomicAdd(&TLr[row0 + wi + b * 16 + l16], l);
        }
    }
}

// ---------------- fallback matmul (R2-proven LDS version), used when ws is small ----------------
template <int PASS, bool STORE>
__global__ __launch_bounds__(256) void k_mat(
    const __hip_bfloat16* __restrict__ Yb, const __hip_bfloat16* __restrict__ Xb,
    const float* __restrict__ yn, const float* __restrict__ xn,
    float* __restrict__ pos, float* __restrict__ R, float* __restrict__ TLr,
    float* __restrict__ sc, h16x4* __restrict__ Eg)
{
    __shared__ short ldsY[TILE * LDP];
    __shared__ short ldsX[TILE * LDP];
    __shared__ __align__(16) float ldsYn[TILE];
    __shared__ __align__(16) float ldsXn[TILE];
    __shared__ float rowA[TILE], rowB[TILE];
    __shared__ float wred[4][3];

    const int tid = threadIdx.x;
    const int bm = blockIdx.y, bn = blockIdx.x;
    const int row0 = bm * TILE, col0 = bn * TILE;
    const int lane = tid & 63, wave = tid >> 6;
    const int wj = (wave >> 1) * 64, wi = (wave & 1) * 64;
    const int l16 = lane & 15, quad = lane >> 4;

    if (tid < TILE) {
        ldsYn[tid] = yn[row0 + tid];
        ldsXn[tid] = xn[col0 + tid];
        if (PASS == 1) { rowA[tid] = 0.f; rowB[tid] = 0.f; }
        else { float p = pos[row0 + tid]; rowA[tid] = p; rowB[tid] = fast_exp2(p * LOG2E); }
    }
    const float LB = (PASS == 2) ? sc[3] : 0.f;
    const float C2 = (PASS == 2) ? 2.f * fast_exp2(LB * LOG2E) : 0.f;

    f32x4 acc[4][4];
#pragma unroll
    for (int a = 0; a < 4; a++)
#pragma unroll
        for (int b = 0; b < 4; b++) acc[a][b] = f32x4{0.f, 0.f, 0.f, 0.f};

#pragma unroll
    for (int ks = 0; ks < 2; ++ks) {
        if (ks) __syncthreads();
        const int4* gy = (const int4*)(Yb + (size_t)row0 * D + ks * 64);
        const int4* gx = (const int4*)(Xb + (size_t)col0 * D + ks * 64);
#pragma unroll
        for (int u = 0; u < 4; u++) {
            int e = tid + u * 256;
            int r = e >> 3, c = e & 7;
            *(int4*)&ldsY[r * LDP + c * 8] = gy[r * 16 + c];
            *(int4*)&ldsX[r * LDP + c * 8] = gx[r * 16 + c];
        }
        __syncthreads();
#pragma unroll
        for (int kk = 0; kk < 2; ++kk) {
            short8 af[4], bf[4];
#pragma unroll
            for (int t = 0; t < 4; t++) {
                af[t] = *(const short8*)&ldsX[(wj + t * 16 + l16) * LDP + kk * 32 + quad * 8];
                bf[t] = *(const short8*)&ldsY[(wi + t * 16 + l16) * LDP + kk * 32 + quad * 8];
            }
#pragma unroll
            for (int a = 0; a < 4; a++)
#pragma unroll
                for (int b = 0; b < 4; b++)
                    acc[a][b] = __builtin_amdgcn_mfma_f32_16x16x32_bf16(af[a], bf[b], acc[a][b], 0, 0, 0);
        }
    }

    if (PASS == 1) {
        float sL[4] = {0.f, 0.f, 0.f, 0.f}, sE[4] = {0.f, 0.f, 0.f, 0.f};
        const bool diag = (row0 == col0);
#pragma unroll
        for (int a = 0; a < 4; a++) {
            const int jl = wj + a * 16 + quad * 4;
            const f32x4 xnv = *(const f32x4*)&ldsXn[jl];
#pragma unroll
            for (int b = 0; b < 4; b++) {
                const int il = wi + b * 16 + l16;
                const float ynv = ldsYn[il];
#pragma unroll
                for (int r = 0; r < 4; r++) {
                    float s2 = fmaxf(fmaf(-2.f, acc[a][b][r], ynv + xnv[r]), 0.f);
                    float t = 1.f + s2;
                    float lg = fast_log2(t);
                    float e = fast_rcp(t);
                    sL[b] += lg;
                    sE[b] += e;
                    if (diag && il == jl + r) pos[row0 + il] = -LN2 * lg;
                }
            }
        }
#pragma unroll
        for (int b = 0; b < 4; b++) {
            sL[b] += __shfl_xor(sL[b], 16); sL[b] += __shfl_xor(sL[b], 32);
            sE[b] += __shfl_xor(sE[b], 16); sE[b] += __shfl_xor(sE[b], 32);
            if (lane < 16) {
                atomicAdd(&rowA[wi + b * 16 + l16], sL[b]);
                atomicAdd(&rowB[wi + b * 16 + l16], sE[b]);
            }
        }
        __syncthreads();
        if (tid < TILE) {
            atomicAdd(&TLr[row0 + tid], rowA[tid]);
            atomicAdd(&R[row0 + tid], rowB[tid]);
        }
    } else {
        float sw = 0.f, sp = 0.f, sq = 0.f;
#pragma unroll
        for (int b = 0; b < 4; b++) {
            const int il = wi + b * 16 + l16;
            const float ynv = ldsYn[il];
            const float pe  = rowB[il];
#pragma unroll
            for (int a = 0; a < 4; a++) {
                const f32x4 xnv = *(const f32x4*)&ldsXn[wj + a * 16 + quad * 4];
#pragma unroll
                for (int r = 0; r < 4; r++) {
                    float s2 = fmaxf(fmaf(-2.f, acc[a][b][r], ynv + xnv[r]), 0.f);
                    float t = 1.f + s2;
                    float e = fast_rcp(t);
                    float u = pe + e;
                    sw += fast_log2(u);
                    float v = pe * u;
                    sp = fmaf(v, fast_rcp(v + C2), sp);
                    float ue = e * u;
                    sq = fmaf(ue, fast_rcp(ue + C2), sq);
                }
            }
        }
#pragma unroll
        for (int m = 1; m < 64; m <<= 1) { sw += __shfl_xor(sw, m); sp += __shfl_xor(sp, m); sq += __shfl_xor(sq, m); }
        if (lane == 0) { wred[wave][0] = sw; wred[wave][1] = sp; wred[wave][2] = sq; }
        __syncthreads();
        if (tid == 0) {
            float W = 0, P = 0, Q = 0;
            for (int w = 0; w < 4; w++) { W += wred[w][0]; P += wred[w][1]; Q += wred[w][2]; }
            atomicAdd(&sc[0], W); atomicAdd(&sc[1], P); atomicAdd(&sc[2], Q);
        }
    }
}

// ---------------- kernel 2: reduce rows -> LB, TP, diag corrections, pe table ----------------
__device__ __forceinline__ float block_sum(float v, float* sm)
{
#pragma unroll
    for (int m = 1; m < 64; m <<= 1) v += __shfl_xor(v, m);
    if ((threadIdx.x & 63) == 0) sm[threadIdx.x >> 6] = v;
    __syncthreads();
    float r = 0.f;
    if (threadIdx.x == 0) r = sm[0] + sm[1] + sm[2] + sm[3];
    __syncthreads();
    return r;  // valid on thread 0
}

__global__ __launch_bounds__(256) void k_mid(
    const float* __restrict__ pos, const float* __restrict__ R,
    const float* __restrict__ TLr, float* __restrict__ sc,
    float* __restrict__ pe_tab)
{
    __shared__ float sm[4];
    __shared__ float bc;
    const int tid = threadIdx.x;
    float sp = 0, sn = 0, tl = 0, ps = 0;
    for (int i = tid; i < N; i += 256) {
        float pv = pos[i], ep = fast_exp2(pv * LOG2E);
        pe_tab[i] = ep;
        sp += ep; sn += R[i] - ep;
        tl += -LN2 * TLr[i] - pv;
        ps += pv;
    }
    sp = block_sum(sp, sm);
    sn = block_sum(sn, sm);
    tl = block_sum(tl, sm);
    ps = block_sum(ps, sm);
    if (tid == 0) {
        const float logM = __logf((float)N * (float)(N - 1));
        float lb2 = __logf(sn) - logM;
        float lb1 = __logf(0.5f * ((float)(N - 1) * sp + sn)) - logM;
        float LB = lb1 + lb2;
        sc[3] = LB; sc[4] = ps; sc[5] = tl;
        bc = LB;
    }
    __syncthreads();
    const float LB = bc;
    float tp = 0, sgd = 0;
    for (int i = tid; i < N; i += 256) {
        float pv = pos[i], ep = fast_exp2(pv * LOG2E);
        float Roff = R[i] - ep;
        float pf = pv - LB + __logf(0.5f * ((float)(N - 1) * ep + Roff)) - __logf((float)(N - 1));
        tp += sig_nl2(-pf * LOG2E);
        sgd += sig_nl2(-(2.f * pv - LB) * LOG2E);
    }
    tp = block_sum(tp, sm);
    sgd = block_sum(sgd, sm);
    if (tid == 0) { sc[6] = tp / (float)N; sc[7] = sgd; }
}

// ---------------- streaming pass 2: 16B loads, product-log, 3 global sums ----------------
// 16B slot s: l16 = s&15, U = s>>6: b2=U&1, w=(U>>3)&3, bm=(U>>5)&31
// i0 = bm*128 + (w&1)*64 + b2*32 + l16; elements 0..3 -> i0, 4..7 -> i0+16
__global__ __launch_bounds__(256) void k_sig2(
    const h16x8* __restrict__ Eg, const float* __restrict__ pe_tab,
    const float* __restrict__ sc, float* __restrict__ wpart)
{
    __shared__ float wred[4][3];
    const int tid = threadIdx.x, bid = blockIdx.x;
    const float C2 = 2.f * fast_exp2(sc[3] * LOG2E);
    float sw = 0.f, sp = 0.f, sq = 0.f;
    unsigned s = (unsigned)bid * 256u + (unsigned)tid;
#pragma unroll 2
    for (int it = 0; it < 8; ++it, s += 262144u) {
        h16x8 hv = Eg[s];
        unsigned U = s >> 6;
        int i0 = (int)(((U >> 5) & 31u) * 128u + ((U >> 3) & 1u) * 64u + (U & 1u) * 32u + (s & 15u));
        float pe0 = pe_tab[i0], pe1 = pe_tab[i0 + 16];
        float prod = 1.f;
#pragma unroll
        for (int r = 0; r < 8; r++) {
            float pe = (r < 4) ? pe0 : pe1;
            float e = (float)hv[r];
            float u = pe + e;
            prod *= u;                                  // u >= pe >= ~1/450; prod^8 >= ~2e-22
            float v = pe * u;
            sp = fmaf(v, fast_rcp(v + C2), sp);         // sigmoid(pos + way - LB)
            float ue = e * u;
            sq = fmaf(ue, fast_rcp(ue + C2), sq);       // sigmoid(way + L - LB)
        }
        sw += fast_log2(prod);                          // sum of log2(pe+e)
    }
    const int lane = tid & 63, wave = tid >> 6;
#pragma unroll
    for (int m = 1; m < 64; m <<= 1) { sw += __shfl_xor(sw, m); sp += __shfl_xor(sp, m); sq += __shfl_xor(sq, m); }
    if (lane == 0) { wred[wave][0] = sw; wred[wave][1] = sp; wred[wave][2] = sq; }
    __syncthreads();
    if (tid == 0) {
        float W = 0, P = 0, Q = 0;
        for (int w = 0; w < 4; w++) { W += wred[w][0]; P += wred[w][1]; Q += wred[w][2]; }
        wpart[bid * 3 + 0] = W; wpart[bid * 3 + 1] = P; wpart[bid * 3 + 2] = Q;
    }
}

// ---------------- finalize 9 outputs (reduces k_sig2 partials if nparts>0) ----------------
__global__ __launch_bounds__(256) void k_fin(
    const float* __restrict__ sc, const float* __restrict__ wpart, int nparts,
    float* __restrict__ out)
{
    __shared__ float sm[4];
    const int tid = threadIdx.x;
    float W, P, Q;
    if (nparts > 0) {
        float w = 0, p = 0, q = 0;
        for (int r = tid; r < nparts; r += 256) {
            w += wpart[r * 3 + 0]; p += wpart[r * 3 + 1]; q += wpart[r * 3 + 2];
        }
        W = block_sum(w, sm); P = block_sum(p, sm); Q = block_sum(q, sm);
    } else {
        W = sc[0]; P = sc[1]; Q = sc[2];
    }
    if (tid == 0) {
        const float M = (float)N * (float)(N - 1);
        float Wo  = LN2 * (W - (float)N * (float)N) - sc[4];  // off-diag sum of way
        float SGP = P - sc[7];
        float SGN = Q - sc[7];
        float LB = sc[3], Sp = sc[4], TL = sc[5], TP = sc[6];
        float o0 = Sp / (float)N + Wo / M - LB;
        float o1 = Wo / M + TL / M - LB;
        float o2 = SGP / M, o3 = SGN / M;
        float FP = o3;
        out[0] = o0;
        out[1] = o1;
        out[2] = o2;
        out[3] = o3;
        out[4] = (TP + (1.f - FP)) * 0.5f;
        out[5] = TP;
        out[6] = TP / (TP + FP);
        out[7] = LB;
        out[8] = -o0 + 2.0f;
    }
}

extern "C" void kernel_launch(void* const* d_in, const int* in_sizes, int n_in,
                              void* d_out, int out_size, void* d_ws, size_t ws_size,
                              hipStream_t stream)
{
    const float* X = (const float*)d_in[0];  // z_x (j / columns of logits)
    const float* Y = (const float*)d_in[1];  // z_y (i / rows of logits)
    float* out = (float*)d_out;

    char* ws = (char*)d_ws;
    __hip_bfloat16* Yb = (__hip_bfloat16*)(ws);
    __hip_bfloat16* Xb = (__hip_bfloat16*)(ws + (1 << 20));
    float* yn   = (float*)(ws + (2 << 20));
    float* xn   = yn + N;
    float* pos  = xn + N;
    float* R    = pos + N;
    float* TLr  = R + N;
    float* pe   = TLr + N;
    float* sc   = pe + N;          // 16 scalars
    float* wpart = sc + 16;        // 1024*3 partials
    h16x8* Eg8  = (h16x8*)(ws + (4 << 20));   // 32 MB E-file
    h16x4* Eg4  = (h16x4*)(ws + (4 << 20));

    const bool big = ws_size >= ((size_t)37 << 20);

    k_prep<<<N, 128, 0, stream>>>(X, Y, Xb, Yb, xn, yn, R, TLr, sc);
    if (big) {
        k_main<<<dim3(N / TILE, N / TILE), 256, 0, stream>>>(Yb, Xb, yn, xn, pos, R, TLr, Eg8);
        k_mid<<<1, 256, 0, stream>>>(pos, R, TLr, sc, pe);
        k_sig2<<<1024, 256, 0, stream>>>(Eg8, pe, sc, wpart);
        k_fin<<<1, 256, 0, stream>>>(sc, wpart, 1024, out);
    } else {
        k_mat<1, false><<<dim3(N / TILE, N / TILE), 256, 0, stream>>>(Yb, Xb, yn, xn, pos, R, TLr, sc, Eg4);
        k_mid<<<1, 256, 0, stream>>>(pos, R, TLr, sc, pe);
        k_mat<2, false><<<dim3(N / TILE, N / TILE), 256, 0, stream>>>(Yb, Xb, yn, xn, pos, R, TLr, sc, Eg4);
        k_fin<<<1, 256, 0, stream>>>(sc, wpart, 0, out);
    }
}

// Round 6
// 99.618 us; speedup vs baseline: 1.1081x; 1.1081x over previous
//
#include <hip/hip_runtime.h>
#include <hip/hip_bf16.h>

#define N 4096
#define D 128
#define TILE 128
#define NFF 4096.0f

typedef __attribute__((ext_vector_type(8))) short short8;
typedef __attribute__((ext_vector_type(4))) float f32x4;

#define LOG2E 1.44269504088896340736f
#define LN2   0.69314718055994530942f

#if __has_builtin(__builtin_amdgcn_rcpf)
__device__ __forceinline__ float fast_rcp(float x) { return __builtin_amdgcn_rcpf(x); }
#else
__device__ __forceinline__ float fast_rcp(float x) { return 1.f / x; }
#endif
#if __has_builtin(__builtin_amdgcn_logf)
__device__ __forceinline__ float fast_log2(float x) { return __builtin_amdgcn_logf(x); }
#else
__device__ __forceinline__ float fast_log2(float x) { return __log2f(x); }
#endif
#if __has_builtin(__builtin_amdgcn_exp2f)
__device__ __forceinline__ float fast_exp2(float x) { return __builtin_amdgcn_exp2f(x); }
#else
__device__ __forceinline__ float fast_exp2(float x) { return exp2f(x); }
#endif

__device__ __forceinline__ float sigx(float x) {   // sigmoid(x)
    return fast_rcp(1.f + fast_exp2(-x * LOG2E));
}

// ---------------- kernel 0: cast to bf16, exact fp32 row norms, zero accumulators ----------------
__global__ __launch_bounds__(128) void k_prep(
    const float* __restrict__ X, const float* __restrict__ Y,
    __hip_bfloat16* __restrict__ Xb, __hip_bfloat16* __restrict__ Yb,
    float* __restrict__ xn, float* __restrict__ yn,
    float* __restrict__ g5, float* __restrict__ sc, int* __restrict__ syncv)
{
    const int row = blockIdx.x, t = threadIdx.x;
    const float vx = X[row * D + t], vy = Y[row * D + t];
    Xb[row * D + t] = __float2bfloat16(vx);
    Yb[row * D + t] = __float2bfloat16(vy);
    float px = vx * vx, py = vy * vy;
#pragma unroll
    for (int m = 1; m < 64; m <<= 1) { px += __shfl_xor(px, m); py += __shfl_xor(py, m); }
    __shared__ float s[2][2];
    if ((t & 63) == 0) { s[t >> 6][0] = px; s[t >> 6][1] = py; }
    __syncthreads();
    if (t == 0) { xn[row] = s[0][0] + s[1][0]; yn[row] = s[0][1] + s[1][1]; }
    const int g = row * 128 + t;
    if (g < 5 * N) g5[g] = 0.f;
    if (g < 16) sc[g] = 0.f;
    if (g < 4) syncv[g] = 0;
}

// ---------------- main pass: barrier-light, LDS-free MFMA + moment epilogue ----------------
// acc[a][b][r]: j = col0 + wj + a*16 + quad*4 + r,  i = row0 + wi + b*16 + l16
// Per-row outputs (g5[v*N + i]): v0 = sum 1/t (= sum e^L), v1..v4 = sum c^k, c = log2(t/256)
__global__ __launch_bounds__(256) void k_main(
    const __hip_bfloat16* __restrict__ Yb, const __hip_bfloat16* __restrict__ Xb,
    const float* __restrict__ yn, const float* __restrict__ xn,
    float* __restrict__ pos, float* __restrict__ g5)
{
    __shared__ float rowAcc[5][TILE];
    const int tid = threadIdx.x;
    const int bm = blockIdx.y, bn = blockIdx.x;
    const int row0 = bm * TILE, col0 = bn * TILE;   // row0 -> i (Y), col0 -> j (X)
    const int lane = tid & 63, wave = tid >> 6;
    const int wj = (wave >> 1) * 64, wi = (wave & 1) * 64;
    const int l16 = lane & 15, quad = lane >> 4;

    for (int v = tid; v < 5 * TILE; v += 256) (&rowAcc[0][0])[v] = 0.f;
    __syncthreads();

    f32x4 acc[4][4];
#pragma unroll
    for (int a = 0; a < 4; a++)
#pragma unroll
        for (int b = 0; b < 4; b++) acc[a][b] = f32x4{0.f, 0.f, 0.f, 0.f};

    const short8* Xg = (const short8*)(Xb + (size_t)col0 * D);   // j side (A)
    const short8* Yg = (const short8*)(Yb + (size_t)row0 * D);   // i side (B)

#pragma unroll
    for (int kk = 0; kk < 4; ++kk) {
        short8 af[4], bf[4];
#pragma unroll
        for (int t = 0; t < 4; t++) {
            af[t] = Xg[(wj + t * 16 + l16) * (D / 8) + kk * 4 + quad];
            bf[t] = Yg[(wi + t * 16 + l16) * (D / 8) + kk * 4 + quad];
        }
#pragma unroll
        for (int a = 0; a < 4; a++)
#pragma unroll
            for (int b = 0; b < 4; b++)
                acc[a][b] = __builtin_amdgcn_mfma_f32_16x16x32_bf16(af[a], bf[b], acc[a][b], 0, 0, 0);
    }

    float ynv[4];
#pragma unroll
    for (int b = 0; b < 4; b++) ynv[b] = yn[row0 + wi + b * 16 + l16];

    float sE[4] = {0.f, 0.f, 0.f, 0.f}, s1[4] = {0.f, 0.f, 0.f, 0.f};
    float s2[4] = {0.f, 0.f, 0.f, 0.f}, s3[4] = {0.f, 0.f, 0.f, 0.f}, s4[4] = {0.f, 0.f, 0.f, 0.f};
    const bool diagw = (bm == bn) && (wi == wj);

#pragma unroll
    for (int a = 0; a < 4; a++) {
        const f32x4 xq = *(const f32x4*)&xn[col0 + wj + a * 16 + quad * 4];
        f32x4 x1;
#pragma unroll
        for (int r = 0; r < 4; r++) x1[r] = xq[r] + 1.f;
#pragma unroll
        for (int b = 0; b < 4; b++) {
#pragma unroll
            for (int r = 0; r < 4; r++) {
                float t = fmaxf(fmaf(-2.f, acc[a][b][r], ynv[b] + x1[r]), 1.f);
                float e = fast_rcp(t);                        // e^L exactly
                float c = fast_log2(t * 0.00390625f);         // log2(t) - 8, centered
                float c2 = c * c;
                sE[b] += e;
                s1[b] += c;
                s2[b] += c2;
                s3[b] = fmaf(c, c2, s3[b]);
                s4[b] = fmaf(c2, c2, s4[b]);
                if (diagw && (a * 16 + quad * 4 + r) == (b * 16 + l16))
                    pos[row0 + wi + b * 16 + l16] = -LN2 * (c + 8.f);
            }
        }
    }

#pragma unroll
    for (int b = 0; b < 4; b++) {
        const int il = wi + b * 16 + l16;
        float vE = sE[b], v1 = s1[b], v2 = s2[b], v3 = s3[b], v4 = s4[b];
        vE += __shfl_xor(vE, 16); vE += __shfl_xor(vE, 32);
        v1 += __shfl_xor(v1, 16); v1 += __shfl_xor(v1, 32);
        v2 += __shfl_xor(v2, 16); v2 += __shfl_xor(v2, 32);
        v3 += __shfl_xor(v3, 16); v3 += __shfl_xor(v3, 32);
        v4 += __shfl_xor(v4, 16); v4 += __shfl_xor(v4, 32);
        if (lane < 16) {
            atomicAdd(&rowAcc[0][il], vE);
            atomicAdd(&rowAcc[1][il], v1);
            atomicAdd(&rowAcc[2][il], v2);
            atomicAdd(&rowAcc[3][il], v3);
            atomicAdd(&rowAcc[4][il], v4);
        }
    }
    __syncthreads();
    for (int idx = tid; idx < 5 * TILE; idx += 256) {
        int v = idx >> 7, i = idx & 127;
        atomicAdd(&g5[v * N + row0 + i], rowAcc[v][i]);
    }
}

// ---------------- block reduction helper ----------------
__device__ __forceinline__ float block_sum(float v, float* sm)
{
#pragma unroll
    for (int m = 1; m < 64; m <<= 1) v += __shfl_xor(v, m);
    if ((threadIdx.x & 63) == 0) sm[threadIdx.x >> 6] = v;
    __syncthreads();
    float r = 0.f;
    if (threadIdx.x == 0) r = sm[0] + sm[1] + sm[2] + sm[3];
    __syncthreads();
    return r;  // valid on thread 0
}

// ---------------- k_post: LB (exact) + moment-based W/P/Q + outputs. 16 blocks, 1 row/thread ----------------
__global__ __launch_bounds__(256) void k_post(
    const float* __restrict__ pos, const float* __restrict__ g5,
    float* __restrict__ sc, int* __restrict__ syncv, float* __restrict__ out)
{
    __shared__ float sm[4];
    __shared__ float sLB;
    const int tid = threadIdx.x;
    const int i = blockIdx.x * 256 + tid;
    const int nb = gridDim.x;

    const float p  = pos[i];
    const float pe = fast_exp2(p * LOG2E);
    const float E  = g5[i];
    const float C1 = g5[N + i];

    // ---- phase A: exact global reductions -> LB ----
    float bs;
    bs = block_sum(pe, sm);                            if (tid == 0) atomicAdd(&sc[10], bs);
    bs = block_sum(E - pe, sm);                        if (tid == 0) atomicAdd(&sc[11], bs);
    bs = block_sum(-LN2 * (8.f * NFF + C1) - p, sm);   if (tid == 0) atomicAdd(&sc[12], bs);
    bs = block_sum(p, sm);                             if (tid == 0) atomicAdd(&sc[13], bs);
    __threadfence();
    if (tid == 0) {
        int c = __hip_atomic_fetch_add(&syncv[0], 1, __ATOMIC_ACQ_REL, __HIP_MEMORY_SCOPE_AGENT);
        if (c == nb - 1) {
            float S_pos = __hip_atomic_load(&sc[10], __ATOMIC_RELAXED, __HIP_MEMORY_SCOPE_AGENT);
            float S_neg = __hip_atomic_load(&sc[11], __ATOMIC_RELAXED, __HIP_MEMORY_SCOPE_AGENT);
            float TLs   = __hip_atomic_load(&sc[12], __ATOMIC_RELAXED, __HIP_MEMORY_SCOPE_AGENT);
            float Sp    = __hip_atomic_load(&sc[13], __ATOMIC_RELAXED, __HIP_MEMORY_SCOPE_AGENT);
            const float logM = __logf(NFF * (NFF - 1.f));
            float lb2 = __logf(S_neg) - logM;
            float lb1 = __logf(0.5f * ((NFF - 1.f) * S_pos + S_neg)) - logM;
            float LB = lb1 + lb2;
            __hip_atomic_store(&sc[3], LB,  __ATOMIC_RELAXED, __HIP_MEMORY_SCOPE_AGENT);
            __hip_atomic_store(&sc[4], Sp,  __ATOMIC_RELAXED, __HIP_MEMORY_SCOPE_AGENT);
            __hip_atomic_store(&sc[5], TLs, __ATOMIC_RELAXED, __HIP_MEMORY_SCOPE_AGENT);
            __hip_atomic_store(&syncv[1], 1, __ATOMIC_RELEASE, __HIP_MEMORY_SCOPE_AGENT);
        }
        while (__hip_atomic_load(&syncv[1], __ATOMIC_ACQUIRE, __HIP_MEMORY_SCOPE_AGENT) == 0)
            __builtin_amdgcn_s_sleep(8);
        sLB = __hip_atomic_load(&sc[3], __ATOMIC_RELAXED, __HIP_MEMORY_SCOPE_AGENT);
    }
    __syncthreads();
    const float LB = sLB;

    // ---- exact per-row: TP term and diagonal corrections ----
    float Roff = E - pe;
    float pf = p - LB + __logf(0.5f * ((NFF - 1.f) * pe + Roff)) - __logf(NFF - 1.f);
    float tp  = sigx(pf);
    float sgd = sigx(2.f * p - LB);

    // ---- moment-based row sums (4th-order Taylor about row mean of l) ----
    const float C2v = g5[2 * N + i], C3v = g5[3 * N + i], C4v = g5[4 * N + i];
    const float inN = 1.f / NFF;
    float m1 = C1 * inN, e2 = C2v * inN, e3 = C3v * inN, e4 = C4v * inN;
    float k2 = e2 - m1 * m1;
    float k3 = e3 - 3.f * m1 * e2 + 2.f * m1 * m1 * m1;
    float k4 = e4 - 4.f * m1 * e3 + 6.f * m1 * m1 * e2 - 3.f * m1 * m1 * m1 * m1;
    float mu2 = LN2 * LN2 * k2;
    float mu3 = -LN2 * LN2 * LN2 * k3;
    float mu4 = LN2 * LN2 * LN2 * LN2 * k4;
    float mlam = 8.f + m1;                 // mean log2(t)
    float ml = -LN2 * mlam;                // mean l
    float eml = fast_exp2(-mlam);          // e^{ml}
    float den = pe + eml;
    float s = eml * fast_rcp(den);         // sigma(ml - p) = way'
    float w = LN2 * (fast_log2(den) - 1.f);  // way(ml) = ln(0.5*(pe+e^ml))
    float s1d = s * (1.f - s);
    float a2 = s1d, a3 = s1d * (1.f - 2.f * s), a4 = s1d * (1.f - 6.f * s1d);

    float g = sigx(p + w - LB);
    float g1 = g * (1.f - g), g2 = g1 * (1.f - 2.f * g), g3 = g1 * (1.f - 6.f * g1);
    float g4 = g1 * (1.f - 2.f * g) * (1.f - 12.f * g1);
    float ss = s * s;
    float FP2 = g2 * ss + g1 * a2;
    float FP3 = g3 * ss * s + 3.f * g2 * s * a2 + g1 * a3;
    float FP4 = g4 * ss * ss + 6.f * g3 * ss * a2 + g2 * (3.f * a2 * a2 + 4.f * s * a3) + g1 * a4;

    float h = sigx(w + ml - LB);
    float h1 = h * (1.f - h), h2 = h1 * (1.f - 2.f * h), h3 = h1 * (1.f - 6.f * h1);
    float h4 = h1 * (1.f - 2.f * h) * (1.f - 12.f * h1);
    float b1 = 1.f + s, bb = b1 * b1;
    float FQ2 = h2 * bb + h1 * a2;
    float FQ3 = h3 * bb * b1 + 3.f * h2 * b1 * a2 + h1 * a3;
    float FQ4 = h4 * bb * bb + 6.f * h3 * bb * a2 + h2 * (3.f * a2 * a2 + 4.f * b1 * a3) + h1 * a4;

    float Wi = NFF * (w + 0.5f * a2 * mu2 + (1.f / 6.f) * a3 * mu3 + (1.f / 24.f) * a4 * mu4);
    float Pi = NFF * (g + 0.5f * FP2 * mu2 + (1.f / 6.f) * FP3 * mu3 + (1.f / 24.f) * FP4 * mu4);
    float Qi = NFF * (h + 0.5f * FQ2 * mu2 + (1.f / 6.f) * FQ3 * mu3 + (1.f / 24.f) * FQ4 * mu4);

    bs = block_sum(Wi, sm);  if (tid == 0) atomicAdd(&sc[0], bs);
    bs = block_sum(Pi, sm);  if (tid == 0) atomicAdd(&sc[1], bs);
    bs = block_sum(Qi, sm);  if (tid == 0) atomicAdd(&sc[2], bs);
    bs = block_sum(tp, sm);  if (tid == 0) atomicAdd(&sc[6], bs);
    bs = block_sum(sgd, sm); if (tid == 0) atomicAdd(&sc[7], bs);
    __threadfence();
    if (tid == 0) {
        int c = __hip_atomic_fetch_add(&syncv[2], 1, __ATOMIC_ACQ_REL, __HIP_MEMORY_SCOPE_AGENT);
        if (c == nb - 1) {
            float W   = __hip_atomic_load(&sc[0], __ATOMIC_RELAXED, __HIP_MEMORY_SCOPE_AGENT);
            float P   = __hip_atomic_load(&sc[1], __ATOMIC_RELAXED, __HIP_MEMORY_SCOPE_AGENT);
            float Q   = __hip_atomic_load(&sc[2], __ATOMIC_RELAXED, __HIP_MEMORY_SCOPE_AGENT);
            float tps = __hip_atomic_load(&sc[6], __ATOMIC_RELAXED, __HIP_MEMORY_SCOPE_AGENT);
            float sg  = __hip_atomic_load(&sc[7], __ATOMIC_RELAXED, __HIP_MEMORY_SCOPE_AGENT);
            float Sp  = __hip_atomic_load(&sc[4], __ATOMIC_RELAXED, __HIP_MEMORY_SCOPE_AGENT);
            float TLs = __hip_atomic_load(&sc[5], __ATOMIC_RELAXED, __HIP_MEMORY_SCOPE_AGENT);
            const float M = NFF * (NFF - 1.f);
            float Wo  = W - Sp;          // off-diagonal sum of way
            float SGP = P - sg;
            float SGN = Q - sg;
            float TP = tps * (1.f / NFF);
            float o0 = Sp / NFF + Wo / M - LB;
            float o1 = Wo / M + TLs / M - LB;
            float o2 = SGP / M, o3 = SGN / M;
            out[0] = o0;
            out[1] = o1;
            out[2] = o2;
            out[3] = o3;
            out[4] = (TP + 1.f - o3) * 0.5f;
            out[5] = TP;
            out[6] = TP / (TP + o3);
            out[7] = LB;
            out[8] = -o0 + 2.0f;
        }
    }
}

extern "C" void kernel_launch(void* const* d_in, const int* in_sizes, int n_in,
                              void* d_out, int out_size, void* d_ws, size_t ws_size,
                              hipStream_t stream)
{
    const float* X = (const float*)d_in[0];  // z_x (j / columns of logits)
    const float* Y = (const float*)d_in[1];  // z_y (i / rows of logits)
    float* out = (float*)d_out;

    char* ws = (char*)d_ws;
    __hip_bfloat16* Yb = (__hip_bfloat16*)(ws);
    __hip_bfloat16* Xb = (__hip_bfloat16*)(ws + (1 << 20));
    float* yn  = (float*)(ws + (2 << 20));
    float* xn  = yn + N;
    float* pos = xn + N;
    float* g5  = pos + N;          // 5*N per-row accumulators (E, C1..C4)
    float* sc  = g5 + 5 * N;       // 16 scalars
    int*   syncv = (int*)(sc + 16);

    k_prep<<<N, 128, 0, stream>>>(X, Y, Xb, Yb, xn, yn, g5, sc, syncv);
    k_main<<<dim3(N / TILE, N / TILE), 256, 0, stream>>>(Yb, Xb, yn, xn, pos, g5);
    k_post<<<16, 256, 0, stream>>>(pos, g5, sc, syncv, out);
}